// Round 3
// baseline (533.464 us; speedup 1.0000x reference)
//
#include <hip/hip_runtime.h>
#include <hip/hip_bf16.h>
#include <math.h>

#define N_NODES 50000
#define N_EDGES 800000
#define IN_DIM 32
#define HIDDEN 64
#define Z_DIM 32

// ---------------------------------------------------------------------------
// prep: zero degree counters + detect edge_index dtype (int32 vs int64).
// For int64 LE values < 2^31 every odd int32 word is 0; 64 samples suffice.
__global__ void prep_kernel(const int* __restrict__ raw, int* __restrict__ flag,
                            int* __restrict__ cnt) {
    int i = blockIdx.x * 256 + threadIdx.x;
    if (i < N_NODES) cnt[i] = 0;
    if (blockIdx.x == 0 && threadIdx.x < 64) {
        int odd = raw[2 * threadIdx.x + 1];
        unsigned long long b = __ballot(odd != 0);
        if (threadIdx.x == 0) *flag = (b == 0ULL) ? 1 : 0;
    }
}

// convert indices to int32 AND histogram dst degrees in one pass
__global__ void conv_hist_kernel(const void* __restrict__ raw, const int* __restrict__ flag,
                                 int* __restrict__ idx, int* __restrict__ cnt) {
    int i = blockIdx.x * 256 + threadIdx.x;
    if (i >= 2 * N_EDGES) return;
    int v = (*flag) ? (int)((const long long*)raw)[i] : ((const int*)raw)[i];
    idx[i] = v;
    if (i >= N_EDGES) atomicAdd(&cnt[v], 1);    // dst half
}

// single-workgroup scan: rowptr (exclusive prefix of cnt), cursor copy, dinv
__global__ void scan_kernel(const int* __restrict__ cnt, int* __restrict__ rowptr,
                            int* __restrict__ cursor, float* __restrict__ dinv) {
    __shared__ int part[1024];
    const int ITEMS = (N_NODES + 1023) / 1024;     // 49
    int t = threadIdx.x;
    int base = t * ITEMS;
    int sum = 0;
    for (int j = 0; j < ITEMS; j++) {
        int g = base + j;
        if (g < N_NODES) {
            int c = cnt[g];
            sum += c;
            dinv[g] = rsqrtf((float)(c + 1));      // +1 self loop
        }
    }
    part[t] = sum;
    __syncthreads();
    for (int o = 1; o < 1024; o <<= 1) {
        int a = (t >= o) ? part[t - o] : 0;
        __syncthreads();
        part[t] += a;
        __syncthreads();
    }
    int run = part[t] - sum;                       // exclusive offset for this thread
    for (int j = 0; j < ITEMS; j++) {
        int g = base + j;
        if (g < N_NODES) {
            rowptr[g] = run;
            cursor[g] = run;
            run += cnt[g];
        }
    }
    if (t == 0) rowptr[N_NODES] = N_EDGES;
}

__global__ void scatter_kernel(const int* __restrict__ src, const int* __restrict__ dst,
                               int* __restrict__ cursor, int* __restrict__ ssrc) {
    int e = blockIdx.x * 256 + threadIdx.x;
    if (e >= N_EDGES) return;
    int d = dst[e];
    int p = atomicAdd(&cursor[d], 1);
    ssrc[p] = src[e];
}

// ---------------------------------------------------------------------------
// Wave-cooperative aggregation of one node's row: srow[k] = (A h)[v][k],
// returned distributed lane==k (valid for lane < DIN).
// Gather uses float4 lane-split: LPR=DIN/4 lanes cover one row, 64/LPR edges
// in flight per iteration. Butterfly shfl_xor reduces edge-subsets, then a
// permute redistributes float4 components to lane-per-k layout.
template<int DIN>
__device__ __forceinline__ float agg_row(int v, const int* __restrict__ rowptr,
                                         const int* __restrict__ ssrc,
                                         const float* __restrict__ dinv,
                                         const float* __restrict__ h) {
    const int LPR = DIN / 4;          // lanes per row: 16 (D=64) / 8 (D=32)
    const int EPB = 64 / LPR;         // edges per batch: 4 / 8
    int lane = threadIdx.x & 63;
    int q    = lane & (LPR - 1);
    int sub  = lane / LPR;
    int e0 = rowptr[v];
    int e1 = rowptr[v + 1];
    float4 acc = make_float4(0.f, 0.f, 0.f, 0.f);
    for (int e = e0; e < e1; e += EPB) {
        int ee = e + sub;
        int cl = (ee < N_EDGES) ? ee : (N_EDGES - 1);
        int s  = ssrc[cl];
        float w = (ee < e1) ? dinv[s] : 0.0f;
        const float4* row = (const float4*)(h + (size_t)s * DIN);
        float4 hv = row[q];
        acc.x = fmaf(w, hv.x, acc.x);
        acc.y = fmaf(w, hv.y, acc.y);
        acc.z = fmaf(w, hv.z, acc.z);
        acc.w = fmaf(w, hv.w, acc.w);
    }
#pragma unroll
    for (int o = LPR; o < 64; o <<= 1) {
        acc.x += __shfl_xor(acc.x, o);
        acc.y += __shfl_xor(acc.y, o);
        acc.z += __shfl_xor(acc.z, o);
        acc.w += __shfl_xor(acc.w, o);
    }
    // lane k wants component (k&3) of the float4 held (replicated) at q=k>>2
    int srcl = lane >> 2;
    float v0 = __shfl(acc.x, srcl);
    float v1 = __shfl(acc.y, srcl);
    float v2 = __shfl(acc.z, srcl);
    float v3 = __shfl(acc.w, srcl);
    int c = lane & 3;
    float g = (c == 0) ? v0 : (c == 1) ? v1 : (c == 2) ? v2 : v3;
    float dv = dinv[v];
    int hidx = (lane < DIN) ? lane : 0;            // stay in bounds for lanes>=DIN
    float hk = h[(size_t)v * DIN + hidx];
    return dv * fmaf(dv, hk, g);                   // dv*(dv*h_v + sum dinv_s h_s)
}

// ---------------------------------------------------------------------------
// Fused layer: out[v][of] = relu( (A h)[v][:] @ W[DIN,64] + b ), of = lane.
// W column held in VGPRs; aggregated row broadcast via readlane. No LDS.
template<int DIN>
__global__ __launch_bounds__(256, 4) void fused_layer_kernel(
        const int* __restrict__ rowptr, const int* __restrict__ ssrc,
        const float* __restrict__ dinv, const float* __restrict__ h,
        const float* __restrict__ W, const float* __restrict__ b,
        float* __restrict__ out) {
    int lane = threadIdx.x & 63;
    float wcol[DIN];
#pragma unroll
    for (int k = 0; k < DIN; k++) wcol[k] = W[k * 64 + lane];
    float bb = b[lane];
    int wid = (blockIdx.x * blockDim.x + threadIdx.x) >> 6;
    int nw  = (gridDim.x * blockDim.x) >> 6;
    for (int v = wid; v < N_NODES; v += nw) {
        float srow = agg_row<DIN>(v, rowptr, ssrc, dinv, h);
        float acc = bb;
#pragma unroll
        for (int k = 0; k < DIN; k++) acc = fmaf(__shfl(srow, k), wcol[k], acc);
        out[(size_t)v * 64 + lane] = fmaxf(acc, 0.0f);
    }
}

// Fused heads: a2 = (A h2)[v], mu = a2@Wmu+bmu (lanes<32), lv = a2@Wlv+blv
// (lanes>=32), z = mu + exp(0.5 lv)*eps. d_out = [z | mu | lv].
__global__ __launch_bounds__(256, 4) void fused_head_kernel(
        const int* __restrict__ rowptr, const int* __restrict__ ssrc,
        const float* __restrict__ dinv, const float* __restrict__ h,
        const float* __restrict__ Wmu, const float* __restrict__ bmu,
        const float* __restrict__ Wlv, const float* __restrict__ blv,
        const float* __restrict__ eps, float* __restrict__ outz) {
    int lane = threadIdx.x & 63;
    int f = lane & 31;
    bool hi = lane >= 32;
    float wcol[64];
#pragma unroll
    for (int k = 0; k < 64; k++)
        wcol[k] = hi ? Wlv[k * 32 + f] : Wmu[k * 32 + f];
    float bb = hi ? blv[f] : bmu[f];
    float* z  = outz;
    float* mu = outz + (size_t)N_NODES * Z_DIM;
    float* lv = outz + 2 * (size_t)N_NODES * Z_DIM;
    int wid = (blockIdx.x * blockDim.x + threadIdx.x) >> 6;
    int nw  = (gridDim.x * blockDim.x) >> 6;
    for (int v = wid; v < N_NODES; v += nw) {
        float srow = agg_row<64>(v, rowptr, ssrc, dinv, h);
        float acc = bb;
#pragma unroll
        for (int k = 0; k < 64; k++) acc = fmaf(__shfl(srow, k), wcol[k], acc);
        // hi lanes: acc = logvar; compute exp(0.5 lv)*eps, ship to low lanes
        float t = expf(0.5f * acc) * eps[(size_t)v * Z_DIM + f];
        float tlo = __shfl(t, lane | 32);
        size_t o = (size_t)v * Z_DIM + f;
        if (!hi) {
            mu[o] = acc;
            z[o]  = acc + tlo;
        } else {
            lv[o] = acc;
        }
    }
}

// ---------------------------------------------------------------------------
extern "C" void kernel_launch(void* const* d_in, const int* in_sizes, int n_in,
                              void* d_out, int out_size, void* d_ws, size_t ws_size,
                              hipStream_t stream) {
    const float* x   = (const float*)d_in[0];
    const void*  ei  = d_in[1];
    const float* W1  = (const float*)d_in[2];
    const float* b1  = (const float*)d_in[3];
    const float* W2  = (const float*)d_in[4];
    const float* b2  = (const float*)d_in[5];
    const float* Wmu = (const float*)d_in[6];
    const float* bmu = (const float*)d_in[7];
    const float* Wlv = (const float*)d_in[8];
    const float* blv = (const float*)d_in[9];
    const float* eps = (const float*)d_in[10];
    float* out = (float*)d_out;
    (void)in_sizes; (void)n_in; (void)out_size; (void)ws_size;

    char* ws = (char*)d_ws;
    size_t off = 0;
    auto alloc = [&](size_t bytes) -> void* {
        void* p = ws + off;
        off += (bytes + 255) & ~(size_t)255;
        return p;
    };
    int*   ssrc   = (int*)alloc(sizeof(int) * N_EDGES);          // 3.2 MB
    int*   rowptr = (int*)alloc(sizeof(int) * (N_NODES + 1));
    int*   cursor = (int*)alloc(sizeof(int) * N_NODES);
    int*   cnt    = (int*)alloc(sizeof(int) * N_NODES);
    float* dinv   = (float*)alloc(sizeof(float) * N_NODES);
    int*   flag   = (int*)alloc(sizeof(int) * 64);
    float* h1     = (float*)alloc(sizeof(float) * (size_t)N_NODES * HIDDEN);  // 12.8 MB
    float* h2     = (float*)alloc(sizeof(float) * (size_t)N_NODES * HIDDEN);  // 12.8 MB
    // converted edge list aliases h2: idx dead after scatter, h2 written later
    int* idx = (int*)h2;
    const int* srcI = idx;
    const int* dstI = idx + N_EDGES;

    prep_kernel<<<(N_NODES + 255) / 256, 256, 0, stream>>>((const int*)ei, flag, cnt);
    conv_hist_kernel<<<(2 * N_EDGES + 255) / 256, 256, 0, stream>>>(ei, flag, idx, cnt);
    scan_kernel<<<1, 1024, 0, stream>>>(cnt, rowptr, cursor, dinv);
    scatter_kernel<<<(N_EDGES + 255) / 256, 256, 0, stream>>>(srcI, dstI, cursor, ssrc);

    const int FB = 2048;   // 8192 waves
    fused_layer_kernel<IN_DIM><<<FB, 256, 0, stream>>>(rowptr, ssrc, dinv, x, W1, b1, h1);
    fused_layer_kernel<HIDDEN><<<FB, 256, 0, stream>>>(rowptr, ssrc, dinv, h1, W2, b2, h2);
    fused_head_kernel<<<FB, 256, 0, stream>>>(rowptr, ssrc, dinv, h2,
                                              Wmu, bmu, Wlv, blv, eps, out);
}

// Round 4
// 384.066 us; speedup vs baseline: 1.3890x; 1.3890x over previous
//
#include <hip/hip_runtime.h>
#include <hip/hip_bf16.h>
#include <math.h>

#define N_NODES 50000
#define N_EDGES 800000
#define IN_DIM 32
#define HIDDEN 64
#define Z_DIM 32
#define SCAN_B 256
#define NB_SCAN ((N_NODES + SCAN_B - 1) / SCAN_B)   // 196

// ---------------------------------------------------------------------------
// prep: zero degree counters + detect edge_index dtype (int32 vs int64).
// For int64 LE values < 2^31 every odd int32 word is 0; 64 samples suffice.
__global__ void prep_kernel(const int* __restrict__ raw, int* __restrict__ flag,
                            int* __restrict__ cnt) {
    int i = blockIdx.x * 256 + threadIdx.x;
    if (i < N_NODES) cnt[i] = 0;
    if (blockIdx.x == 0 && threadIdx.x < 64) {
        int odd = raw[2 * threadIdx.x + 1];
        unsigned long long b = __ballot(odd != 0);
        if (threadIdx.x == 0) *flag = (b == 0ULL) ? 1 : 0;
    }
}

// degree histogram straight off the raw edge_index (uniform branch on dtype)
__global__ void hist_kernel(const void* __restrict__ raw, const int* __restrict__ flag,
                            int* __restrict__ cnt) {
    int e = blockIdx.x * 256 + threadIdx.x;
    if (e >= N_EDGES) return;
    int d = (*flag) ? (int)((const long long*)raw)[N_EDGES + e]
                    : ((const int*)raw)[N_EDGES + e];
    atomicAdd(&cnt[d], 1);
}

// ---------------------------------------------------------------------------
// 3-phase exclusive scan over cnt -> rowptr; also dinv = rsqrt(deg+1).
__global__ void scan1_kernel(const int* __restrict__ cnt, int* __restrict__ pre,
                             int* __restrict__ bsum, float* __restrict__ dinv) {
    __shared__ int s[SCAN_B];
    int t = threadIdx.x;
    int g = blockIdx.x * SCAN_B + t;
    int v = (g < N_NODES) ? cnt[g] : 0;
    if (g < N_NODES) dinv[g] = rsqrtf((float)(v + 1));   // +1 self loop
    s[t] = v;
    __syncthreads();
    for (int o = 1; o < SCAN_B; o <<= 1) {
        int add = (t >= o) ? s[t - o] : 0;
        __syncthreads();
        s[t] += add;
        __syncthreads();
    }
    if (g < N_NODES) pre[g] = s[t] - v;                  // exclusive within block
    if (t == SCAN_B - 1) bsum[blockIdx.x] = s[t];
}

__global__ void scan2_kernel(int* __restrict__ bsum, int nb) {   // single block
    __shared__ int s[256];
    int t = threadIdx.x;
    int v = (t < nb) ? bsum[t] : 0;
    s[t] = v;
    __syncthreads();
    for (int o = 1; o < 256; o <<= 1) {
        int add = (t >= o) ? s[t - o] : 0;
        __syncthreads();
        s[t] += add;
        __syncthreads();
    }
    if (t < nb) bsum[t] = s[t] - v;                      // exclusive block offsets
}

__global__ void scan3_kernel(int* __restrict__ rowptr, const int* __restrict__ bsum,
                             int* __restrict__ cursor) {
    int g = blockIdx.x * SCAN_B + threadIdx.x;
    if (g < N_NODES) {
        int r = rowptr[g] + bsum[blockIdx.x];
        rowptr[g] = r;
        cursor[g] = r;
    }
    if (g == 0) rowptr[N_NODES] = N_EDGES;
}

// counting-sort scatter, reading src/dst straight off raw edge_index
__global__ void scatter_kernel(const void* __restrict__ raw, const int* __restrict__ flag,
                               int* __restrict__ cursor, int* __restrict__ ssrc) {
    int e = blockIdx.x * 256 + threadIdx.x;
    if (e >= N_EDGES) return;
    int s, d;
    if (*flag) {
        s = (int)((const long long*)raw)[e];
        d = (int)((const long long*)raw)[N_EDGES + e];
    } else {
        s = ((const int*)raw)[e];
        d = ((const int*)raw)[N_EDGES + e];
    }
    int p = atomicAdd(&cursor[d], 1);
    ssrc[p] = s;
}

// ---------------------------------------------------------------------------
// Wave-cooperative aggregation of one node's row: srow[k] = (A h)[v][k],
// returned distributed lane==k (valid for lane < DIN).
// Gather uses float4 lane-split: LPR=DIN/4 lanes cover one row, 64/LPR edges
// in flight per iteration. Butterfly shfl_xor reduces edge-subsets, then a
// permute redistributes float4 components to lane-per-k layout.
template<int DIN>
__device__ __forceinline__ float agg_row(int v, const int* __restrict__ rowptr,
                                         const int* __restrict__ ssrc,
                                         const float* __restrict__ dinv,
                                         const float* __restrict__ h) {
    const int LPR = DIN / 4;          // lanes per row: 16 (D=64) / 8 (D=32)
    const int EPB = 64 / LPR;         // edges per batch: 4 / 8
    int lane = threadIdx.x & 63;
    int q    = lane & (LPR - 1);
    int sub  = lane / LPR;
    int e0 = rowptr[v];
    int e1 = rowptr[v + 1];
    float4 acc = make_float4(0.f, 0.f, 0.f, 0.f);
    for (int e = e0; e < e1; e += EPB) {
        int ee = e + sub;
        int cl = (ee < N_EDGES) ? ee : (N_EDGES - 1);
        int s  = ssrc[cl];
        float w = (ee < e1) ? dinv[s] : 0.0f;
        const float4* row = (const float4*)(h + (size_t)s * DIN);
        float4 hv = row[q];
        acc.x = fmaf(w, hv.x, acc.x);
        acc.y = fmaf(w, hv.y, acc.y);
        acc.z = fmaf(w, hv.z, acc.z);
        acc.w = fmaf(w, hv.w, acc.w);
    }
#pragma unroll
    for (int o = LPR; o < 64; o <<= 1) {
        acc.x += __shfl_xor(acc.x, o);
        acc.y += __shfl_xor(acc.y, o);
        acc.z += __shfl_xor(acc.z, o);
        acc.w += __shfl_xor(acc.w, o);
    }
    // lane k wants component (k&3) of the float4 held (replicated) at q=k>>2
    int srcl = lane >> 2;
    float v0 = __shfl(acc.x, srcl);
    float v1 = __shfl(acc.y, srcl);
    float v2 = __shfl(acc.z, srcl);
    float v3 = __shfl(acc.w, srcl);
    int c = lane & 3;
    float g = (c == 0) ? v0 : (c == 1) ? v1 : (c == 2) ? v2 : v3;
    float dv = dinv[v];
    int hidx = (lane < DIN) ? lane : 0;            // stay in bounds for lanes>=DIN
    float hk = h[(size_t)v * DIN + hidx];
    return dv * fmaf(dv, hk, g);                   // dv*(dv*h_v + sum dinv_s h_s)
}

// ---------------------------------------------------------------------------
// Fused layer: out[v][of] = relu( (A h)[v][:] @ W[DIN,64] + b ), of = lane.
// W column held in VGPRs; aggregated row broadcast via shfl. No LDS.
template<int DIN>
__global__ __launch_bounds__(256, 4) void fused_layer_kernel(
        const int* __restrict__ rowptr, const int* __restrict__ ssrc,
        const float* __restrict__ dinv, const float* __restrict__ h,
        const float* __restrict__ W, const float* __restrict__ b,
        float* __restrict__ out) {
    int lane = threadIdx.x & 63;
    float wcol[DIN];
#pragma unroll
    for (int k = 0; k < DIN; k++) wcol[k] = W[k * 64 + lane];
    float bb = b[lane];
    int wid = (blockIdx.x * blockDim.x + threadIdx.x) >> 6;
    int nw  = (gridDim.x * blockDim.x) >> 6;
    for (int v = wid; v < N_NODES; v += nw) {
        float srow = agg_row<DIN>(v, rowptr, ssrc, dinv, h);
        float acc = bb;
#pragma unroll
        for (int k = 0; k < DIN; k++) acc = fmaf(__shfl(srow, k), wcol[k], acc);
        out[(size_t)v * 64 + lane] = fmaxf(acc, 0.0f);
    }
}

// Fused heads: a2 = (A h2)[v], mu = a2@Wmu+bmu (lanes<32), lv = a2@Wlv+blv
// (lanes>=32), z = mu + exp(0.5 lv)*eps. d_out = [z | mu | lv].
__global__ __launch_bounds__(256, 4) void fused_head_kernel(
        const int* __restrict__ rowptr, const int* __restrict__ ssrc,
        const float* __restrict__ dinv, const float* __restrict__ h,
        const float* __restrict__ Wmu, const float* __restrict__ bmu,
        const float* __restrict__ Wlv, const float* __restrict__ blv,
        const float* __restrict__ eps, float* __restrict__ outz) {
    int lane = threadIdx.x & 63;
    int f = lane & 31;
    bool hi = lane >= 32;
    float wcol[64];
#pragma unroll
    for (int k = 0; k < 64; k++)
        wcol[k] = hi ? Wlv[k * 32 + f] : Wmu[k * 32 + f];
    float bb = hi ? blv[f] : bmu[f];
    float* z  = outz;
    float* mu = outz + (size_t)N_NODES * Z_DIM;
    float* lv = outz + 2 * (size_t)N_NODES * Z_DIM;
    int wid = (blockIdx.x * blockDim.x + threadIdx.x) >> 6;
    int nw  = (gridDim.x * blockDim.x) >> 6;
    for (int v = wid; v < N_NODES; v += nw) {
        float srow = agg_row<64>(v, rowptr, ssrc, dinv, h);
        float acc = bb;
#pragma unroll
        for (int k = 0; k < 64; k++) acc = fmaf(__shfl(srow, k), wcol[k], acc);
        // hi lanes: acc = logvar; compute exp(0.5 lv)*eps, ship to low lanes
        float t = expf(0.5f * acc) * eps[(size_t)v * Z_DIM + f];
        float tlo = __shfl(t, lane | 32);
        size_t o = (size_t)v * Z_DIM + f;
        if (!hi) {
            mu[o] = acc;
            z[o]  = acc + tlo;
        } else {
            lv[o] = acc;
        }
    }
}

// ---------------------------------------------------------------------------
extern "C" void kernel_launch(void* const* d_in, const int* in_sizes, int n_in,
                              void* d_out, int out_size, void* d_ws, size_t ws_size,
                              hipStream_t stream) {
    const float* x   = (const float*)d_in[0];
    const void*  ei  = d_in[1];
    const float* W1  = (const float*)d_in[2];
    const float* b1  = (const float*)d_in[3];
    const float* W2  = (const float*)d_in[4];
    const float* b2  = (const float*)d_in[5];
    const float* Wmu = (const float*)d_in[6];
    const float* bmu = (const float*)d_in[7];
    const float* Wlv = (const float*)d_in[8];
    const float* blv = (const float*)d_in[9];
    const float* eps = (const float*)d_in[10];
    float* out = (float*)d_out;
    (void)in_sizes; (void)n_in; (void)out_size; (void)ws_size;

    char* ws = (char*)d_ws;
    size_t off = 0;
    auto alloc = [&](size_t bytes) -> void* {
        void* p = ws + off;
        off += (bytes + 255) & ~(size_t)255;
        return p;
    };
    int*   ssrc   = (int*)alloc(sizeof(int) * N_EDGES);          // 3.2 MB
    int*   rowptr = (int*)alloc(sizeof(int) * (N_NODES + 1));
    int*   cursor = (int*)alloc(sizeof(int) * N_NODES);
    int*   cnt    = (int*)alloc(sizeof(int) * N_NODES);
    float* dinv   = (float*)alloc(sizeof(float) * N_NODES);
    int*   flag   = (int*)alloc(sizeof(int) * 64);
    int*   bsum   = (int*)alloc(sizeof(int) * 256);
    float* h1     = (float*)alloc(sizeof(float) * (size_t)N_NODES * HIDDEN);  // 12.8 MB
    float* h2     = (float*)alloc(sizeof(float) * (size_t)N_NODES * HIDDEN);  // 12.8 MB

    prep_kernel<<<(N_NODES + 255) / 256, 256, 0, stream>>>((const int*)ei, flag, cnt);
    hist_kernel<<<(N_EDGES + 255) / 256, 256, 0, stream>>>(ei, flag, cnt);
    scan1_kernel<<<NB_SCAN, SCAN_B, 0, stream>>>(cnt, rowptr, bsum, dinv);
    scan2_kernel<<<1, 256, 0, stream>>>(bsum, NB_SCAN);
    scan3_kernel<<<NB_SCAN, SCAN_B, 0, stream>>>(rowptr, bsum, cursor);
    scatter_kernel<<<(N_EDGES + 255) / 256, 256, 0, stream>>>(ei, flag, cursor, ssrc);

    const int FB = 2048;   // 8192 waves
    fused_layer_kernel<IN_DIM><<<FB, 256, 0, stream>>>(rowptr, ssrc, dinv, x, W1, b1, h1);
    fused_layer_kernel<HIDDEN><<<FB, 256, 0, stream>>>(rowptr, ssrc, dinv, h1, W2, b2, h2);
    fused_head_kernel<<<FB, 256, 0, stream>>>(rowptr, ssrc, dinv, h2,
                                              Wmu, bmu, Wlv, blv, eps, out);
}

// Round 5
// 338.729 us; speedup vs baseline: 1.5749x; 1.1338x over previous
//
#include <hip/hip_runtime.h>
#include <hip/hip_bf16.h>
#include <math.h>

#define N_NODES 50000
#define N_EDGES 800000
#define IN_DIM 32
#define HIDDEN 64
#define Z_DIM 32
#define SCAN_B 256
#define NB_SCAN ((N_NODES + SCAN_B - 1) / SCAN_B)   // 196

// ---------------------------------------------------------------------------
// prep: zero degree counters + detect edge_index dtype (int32 vs int64).
// For int64 LE values < 2^31 every odd int32 word is 0; 64 samples suffice.
__global__ void prep_kernel(const int* __restrict__ raw, int* __restrict__ flag,
                            int* __restrict__ cnt) {
    int i = blockIdx.x * 256 + threadIdx.x;
    if (i < N_NODES) cnt[i] = 0;
    if (blockIdx.x == 0 && threadIdx.x < 64) {
        int odd = raw[2 * threadIdx.x + 1];
        unsigned long long b = __ballot(odd != 0);
        if (threadIdx.x == 0) *flag = (b == 0ULL) ? 1 : 0;
    }
}

// degree histogram straight off the raw edge_index (uniform branch on dtype)
__global__ void hist_kernel(const void* __restrict__ raw, const int* __restrict__ flag,
                            int* __restrict__ cnt) {
    int e = blockIdx.x * 256 + threadIdx.x;
    if (e >= N_EDGES) return;
    int d = (*flag) ? (int)((const long long*)raw)[N_EDGES + e]
                    : ((const int*)raw)[N_EDGES + e];
    atomicAdd(&cnt[d], 1);
}

// ---------------------------------------------------------------------------
// 3-phase exclusive scan over cnt -> rowptr; also dinv = rsqrt(deg+1).
__global__ void scan1_kernel(const int* __restrict__ cnt, int* __restrict__ pre,
                             int* __restrict__ bsum, float* __restrict__ dinv) {
    __shared__ int s[SCAN_B];
    int t = threadIdx.x;
    int g = blockIdx.x * SCAN_B + t;
    int v = (g < N_NODES) ? cnt[g] : 0;
    if (g < N_NODES) dinv[g] = rsqrtf((float)(v + 1));   // +1 self loop
    s[t] = v;
    __syncthreads();
    for (int o = 1; o < SCAN_B; o <<= 1) {
        int add = (t >= o) ? s[t - o] : 0;
        __syncthreads();
        s[t] += add;
        __syncthreads();
    }
    if (g < N_NODES) pre[g] = s[t] - v;                  // exclusive within block
    if (t == SCAN_B - 1) bsum[blockIdx.x] = s[t];
}

__global__ void scan2_kernel(int* __restrict__ bsum, int nb) {   // single block
    __shared__ int s[256];
    int t = threadIdx.x;
    int v = (t < nb) ? bsum[t] : 0;
    s[t] = v;
    __syncthreads();
    for (int o = 1; o < 256; o <<= 1) {
        int add = (t >= o) ? s[t - o] : 0;
        __syncthreads();
        s[t] += add;
        __syncthreads();
    }
    if (t < nb) bsum[t] = s[t] - v;                      // exclusive block offsets
}

__global__ void scan3_kernel(int* __restrict__ rowptr, const int* __restrict__ bsum,
                             int* __restrict__ cursor) {
    int g = blockIdx.x * SCAN_B + threadIdx.x;
    if (g < N_NODES) {
        int r = rowptr[g] + bsum[blockIdx.x];
        rowptr[g] = r;
        cursor[g] = r;
    }
    if (g == 0) rowptr[N_NODES] = N_EDGES;
}

// counting-sort scatter; emits packed (src, dinv[src]) per edge so the gather
// loop has a single dependent load level.
__global__ void scatter_kernel(const void* __restrict__ raw, const int* __restrict__ flag,
                               const float* __restrict__ dinv,
                               int* __restrict__ cursor, int2* __restrict__ ep) {
    int e = blockIdx.x * 256 + threadIdx.x;
    if (e >= N_EDGES) return;
    int s, d;
    if (*flag) {
        s = (int)((const long long*)raw)[e];
        d = (int)((const long long*)raw)[N_EDGES + e];
    } else {
        s = ((const int*)raw)[e];
        d = ((const int*)raw)[N_EDGES + e];
    }
    int p = atomicAdd(&cursor[d], 1);
    ep[p] = make_int2(s, __float_as_int(dinv[s]));
}

// ---------------------------------------------------------------------------
// Wave-cooperative aggregation: srow[k] = (A h)[v][k], returned lane==k.
// LPR = DIN/4 lanes cover one row (float4); EPB = 64/LPR edges per batch;
// manual unroll U -> U*EPB edges (rows) in flight per loop trip.
template<int DIN, int U>
__device__ __forceinline__ float agg_row(int v, const int* __restrict__ rowptr,
                                         const int2* __restrict__ ep,
                                         const float* __restrict__ dinv,
                                         const float* __restrict__ h) {
    const int LPR  = DIN / 4;
    const int EPB  = 64 / LPR;
    const int STEP = EPB * U;
    int lane = threadIdx.x & 63;
    int q    = lane & (LPR - 1);
    int sub  = lane / LPR;
    int e0 = rowptr[v];
    int e1 = rowptr[v + 1];
    float4 acc = make_float4(0.f, 0.f, 0.f, 0.f);
    for (int e = e0; e < e1; e += STEP) {
        int2   pr[U];
        float4 hv[U];
        float  w[U];
#pragma unroll
        for (int u = 0; u < U; u++) {
            int ee = e + u * EPB + sub;
            int cl = (ee < N_EDGES) ? ee : (N_EDGES - 1);
            pr[u] = ep[cl];                                 // coalesced 8B pairs
        }
#pragma unroll
        for (int u = 0; u < U; u++) {
            int ee = e + u * EPB + sub;
            w[u]  = (ee < e1) ? __int_as_float(pr[u].y) : 0.0f;
            hv[u] = ((const float4*)(h + (size_t)pr[u].x * DIN))[q];
        }
#pragma unroll
        for (int u = 0; u < U; u++) {
            acc.x = fmaf(w[u], hv[u].x, acc.x);
            acc.y = fmaf(w[u], hv[u].y, acc.y);
            acc.z = fmaf(w[u], hv[u].z, acc.z);
            acc.w = fmaf(w[u], hv[u].w, acc.w);
        }
    }
#pragma unroll
    for (int o = LPR; o < 64; o <<= 1) {
        acc.x += __shfl_xor(acc.x, o);
        acc.y += __shfl_xor(acc.y, o);
        acc.z += __shfl_xor(acc.z, o);
        acc.w += __shfl_xor(acc.w, o);
    }
    // lane k wants component (k&3) of the float4 held at q=k>>2
    int srcl = lane >> 2;
    float v0 = __shfl(acc.x, srcl);
    float v1 = __shfl(acc.y, srcl);
    float v2 = __shfl(acc.z, srcl);
    float v3 = __shfl(acc.w, srcl);
    int c = lane & 3;
    float g = (c == 0) ? v0 : (c == 1) ? v1 : (c == 2) ? v2 : v3;
    float dv = dinv[v];
    int hidx = (lane < DIN) ? lane : 0;
    float hk = h[(size_t)v * DIN + hidx];
    return dv * fmaf(dv, hk, g);                   // dv*(dv*h_v + sum w_s h_s)
}

// ---------------------------------------------------------------------------
// Fused layer: out[v][lane] = relu( (A h)[v][:] @ W[DIN,64] + b ).
// W staged in LDS (conflict-free: consecutive lanes -> consecutive banks).
template<int DIN>
__global__ __launch_bounds__(256) void fused_layer_kernel(
        const int* __restrict__ rowptr, const int2* __restrict__ ep,
        const float* __restrict__ dinv, const float* __restrict__ h,
        const float* __restrict__ W, const float* __restrict__ b,
        float* __restrict__ out) {
    __shared__ float sW[DIN * 64];
    for (int i = threadIdx.x; i < DIN * 64; i += 256) sW[i] = W[i];
    __syncthreads();
    int lane = threadIdx.x & 63;
    float bb = b[lane];
    int wid = (blockIdx.x * blockDim.x + threadIdx.x) >> 6;
    int nw  = (gridDim.x * blockDim.x) >> 6;
    const int U = (DIN == 64) ? 4 : 2;             // 16 rows in flight
    for (int v = wid; v < N_NODES; v += nw) {
        float srow = agg_row<DIN, U>(v, rowptr, ep, dinv, h);
        float acc = bb;
#pragma unroll
        for (int k = 0; k < DIN; k++) acc = fmaf(__shfl(srow, k), sW[k * 64 + lane], acc);
        out[(size_t)v * 64 + lane] = fmaxf(acc, 0.0f);
    }
}

// Fused heads: a2 = (A h2)[v]; lanes<32 -> mu col, lanes>=32 -> lv col;
// z = mu + exp(0.5 lv)*eps. d_out = [z | mu | lv]. Wmu|Wlv packed in LDS.
__global__ __launch_bounds__(256) void fused_head_kernel(
        const int* __restrict__ rowptr, const int2* __restrict__ ep,
        const float* __restrict__ dinv, const float* __restrict__ h,
        const float* __restrict__ Wmu, const float* __restrict__ bmu,
        const float* __restrict__ Wlv, const float* __restrict__ blv,
        const float* __restrict__ eps, float* __restrict__ outz) {
    __shared__ float sW[64 * 64];                  // [k][0:32]=Wmu, [k][32:64]=Wlv
    for (int i = threadIdx.x; i < 64 * 64; i += 256) {
        int k = i >> 6, c = i & 63;
        sW[i] = (c < 32) ? Wmu[k * 32 + c] : Wlv[k * 32 + (c - 32)];
    }
    __syncthreads();
    int lane = threadIdx.x & 63;
    int f = lane & 31;
    bool hi = lane >= 32;
    float bb = hi ? blv[f] : bmu[f];
    float* z  = outz;
    float* mu = outz + (size_t)N_NODES * Z_DIM;
    float* lv = outz + 2 * (size_t)N_NODES * Z_DIM;
    int wid = (blockIdx.x * blockDim.x + threadIdx.x) >> 6;
    int nw  = (gridDim.x * blockDim.x) >> 6;
    for (int v = wid; v < N_NODES; v += nw) {
        float srow = agg_row<64, 4>(v, rowptr, ep, dinv, h);
        float acc = bb;
#pragma unroll
        for (int k = 0; k < 64; k++) acc = fmaf(__shfl(srow, k), sW[k * 64 + lane], acc);
        // hi lanes: acc = logvar; compute exp(0.5 lv)*eps, ship to low lanes
        float t = expf(0.5f * acc) * eps[(size_t)v * Z_DIM + f];
        float tlo = __shfl(t, lane | 32);
        size_t o = (size_t)v * Z_DIM + f;
        if (!hi) {
            mu[o] = acc;
            z[o]  = acc + tlo;
        } else {
            lv[o] = acc;
        }
    }
}

// ---------------------------------------------------------------------------
extern "C" void kernel_launch(void* const* d_in, const int* in_sizes, int n_in,
                              void* d_out, int out_size, void* d_ws, size_t ws_size,
                              hipStream_t stream) {
    const float* x   = (const float*)d_in[0];
    const void*  ei  = d_in[1];
    const float* W1  = (const float*)d_in[2];
    const float* b1  = (const float*)d_in[3];
    const float* W2  = (const float*)d_in[4];
    const float* b2  = (const float*)d_in[5];
    const float* Wmu = (const float*)d_in[6];
    const float* bmu = (const float*)d_in[7];
    const float* Wlv = (const float*)d_in[8];
    const float* blv = (const float*)d_in[9];
    const float* eps = (const float*)d_in[10];
    float* out = (float*)d_out;
    (void)in_sizes; (void)n_in; (void)out_size; (void)ws_size;

    char* ws = (char*)d_ws;
    size_t off = 0;
    auto alloc = [&](size_t bytes) -> void* {
        void* p = ws + off;
        off += (bytes + 255) & ~(size_t)255;
        return p;
    };
    int2*  ep     = (int2*)alloc(sizeof(int2) * N_EDGES);        // 6.4 MB
    int*   rowptr = (int*)alloc(sizeof(int) * (N_NODES + 1));
    int*   cursor = (int*)alloc(sizeof(int) * N_NODES);
    int*   cnt    = (int*)alloc(sizeof(int) * N_NODES);
    float* dinv   = (float*)alloc(sizeof(float) * N_NODES);
    int*   flag   = (int*)alloc(sizeof(int) * 64);
    int*   bsum   = (int*)alloc(sizeof(int) * 256);
    float* h1     = (float*)alloc(sizeof(float) * (size_t)N_NODES * HIDDEN);  // 12.8 MB
    float* h2     = (float*)alloc(sizeof(float) * (size_t)N_NODES * HIDDEN);  // 12.8 MB

    prep_kernel<<<(N_NODES + 255) / 256, 256, 0, stream>>>((const int*)ei, flag, cnt);
    hist_kernel<<<(N_EDGES + 255) / 256, 256, 0, stream>>>(ei, flag, cnt);
    scan1_kernel<<<NB_SCAN, SCAN_B, 0, stream>>>(cnt, rowptr, bsum, dinv);
    scan2_kernel<<<1, 256, 0, stream>>>(bsum, NB_SCAN);
    scan3_kernel<<<NB_SCAN, SCAN_B, 0, stream>>>(rowptr, bsum, cursor);
    scatter_kernel<<<(N_EDGES + 255) / 256, 256, 0, stream>>>(ei, flag, dinv, cursor, ep);

    const int FB = 2048;   // 8192 waves
    fused_layer_kernel<IN_DIM><<<FB, 256, 0, stream>>>(rowptr, ep, dinv, x, W1, b1, h1);
    fused_layer_kernel<HIDDEN><<<FB, 256, 0, stream>>>(rowptr, ep, dinv, h1, W2, b2, h2);
    fused_head_kernel<<<FB, 256, 0, stream>>>(rowptr, ep, dinv, h2,
                                              Wmu, bmu, Wlv, blv, eps, out);
}